// Round 9
// baseline (665.354 us; speedup 1.0000x reference)
//
#include <hip/hip_runtime.h>
#include <hip/hip_cooperative_groups.h>
#include <stdint.h>

namespace cg = cooperative_groups;

#define NN 10000
#define DIN 512
#define KK 1024   // X row length (bf16): [h | mean]
#define KB 2048   // X row bytes
#define CAP 96    // fixed per-node edge capacity (Poisson(16) degrees)
#define GRID 628  // persistent grid: = big-GEMM task count; 3 blocks/CU co-resident
#define NTHR 256

typedef __attribute__((ext_vector_type(8))) short bf16x8;
typedef __attribute__((ext_vector_type(8))) unsigned short u16x8;
typedef __attribute__((ext_vector_type(4))) float f32x4;

__device__ __forceinline__ float bf2f(unsigned short u) {
    return __uint_as_float(((unsigned)u) << 16);
}
__device__ __forceinline__ unsigned short f2bf(float x) {
    unsigned u = __float_as_uint(x);
    return (unsigned short)((u + 0x7fffu + ((u >> 16) & 1u)) >> 16);
}
__device__ __forceinline__ void gload16(const void* g, void* lds) {
    auto gp = reinterpret_cast<const __attribute__((address_space(1))) void*>(
        reinterpret_cast<uintptr_t>(g));
    auto lp = reinterpret_cast<__attribute__((address_space(3))) void*>(
        reinterpret_cast<uintptr_t>(lds));
    __builtin_amdgcn_global_load_lds(gp, lp, 16, 0, 0);
}

struct Args {
    const float* feat;
    const float *ws0, *wn0, *b0, *ws1, *wn1, *b1, *ws2, *wn2, *b2;
    const float* prev;
    const int *esrc, *edst, *high, *low;
    int E, nh, nl;
    unsigned short *XA, *XB, *WT0, *WT1, *WT2, *Pb;
    float* Sf;
    int *eidx, *cursor, *flag, *cl;
    float* out;
};

// ---------- P0: zero cursor|flag|cl (3*NN ints = 7500 int4) ----------
__device__ void zero_phase(const Args& a) {
    int i = blockIdx.x * NTHR + threadIdx.x;
    if (i < 3 * NN / 4) ((int4*)a.cursor)[i] = make_int4(0, 0, 0, 0);
}

// ---------- P1: prep tasks (grid-strided), identical bodies to R8 k_prep ----------
__device__ void prep_phase(const Args& a, char* ldsraw) {
    float (*tile)[33] = (float(*)[33])ldsraw;
    const int t = threadIdx.x;
    const int CB = (a.E + NTHR - 1) / NTHR;
    const int MB = (a.nh + a.nl + NTHR - 1) / NTHR;
    const int T1 = 2500, T2 = T1 + CB, T3 = T2 + MB, T4 = T3 + 1024, T5 = T4 + 64;
    for (int task = blockIdx.x; task < T5; task += GRID) {
        if (task < T1) {
            int idx = task * NTHR + t;             // exactly NN*64 threads
            int row = idx >> 6;
            int col = (idx & 63) * 8;
            const float4* s = (const float4*)(a.feat + (size_t)row * DIN + col);
            float4 v0 = s[0], v1 = s[1];
            u16x8 o;
            o[0] = f2bf(v0.x); o[1] = f2bf(v0.y); o[2] = f2bf(v0.z); o[3] = f2bf(v0.w);
            o[4] = f2bf(v1.x); o[5] = f2bf(v1.y); o[6] = f2bf(v1.z); o[7] = f2bf(v1.w);
            *(u16x8*)(a.XA + (size_t)row * KK + col) = o;
        } else if (task < T2) {
            int i = (task - T1) * NTHR + t;
            if (i < a.E) {
                int d = a.edst[i];
                int pos = atomicAdd(&a.cursor[d], 1);
                if (pos < CAP) a.eidx[d * CAP + pos] = a.esrc[i];
            }
        } else if (task < T3) {
            int i = (task - T2) * NTHR + t;
            if (i < a.nh) {
                atomicOr(&a.flag[a.high[i]], 1);
            } else if (i < a.nh + a.nl) {
                int r = a.low[i - a.nh];
                atomicOr(&a.flag[r], 1);
                atomicAdd(&a.cl[r], 1);
            }
        } else if (task < T4) {
            // WT0/WT1: WT[n][k] = bf16(k<512 ? Ws[k][n] : Wn[k-512][n]), [512][1024]
            int bw = task - T3;
            const float* Ws = (bw < 512) ? a.ws0 : a.ws1;
            const float* Wn = (bw < 512) ? a.wn0 : a.wn1;
            unsigned short* WT = (bw < 512) ? a.WT0 : a.WT1;
            bw &= 511;
            int k0 = (bw & 31) * 32, n0 = (bw >> 5) * 32;
            const float* Wsrc = (k0 < 512) ? Ws : Wn;
            int kb = (k0 < 512) ? k0 : k0 - 512;
            int tx = t & 31, ty = t >> 5;
            for (int i = ty; i < 32; i += 8)
                tile[i][tx] = Wsrc[(size_t)(kb + i) * 512 + n0 + tx];
            __syncthreads();
            for (int i = ty; i < 32; i += 8)
                WT[(size_t)(n0 + i) * 1024 + k0 + tx] = f2bf(tile[tx][i]);
            __syncthreads();                        // protect tile reuse next task
        } else {
            // WT2 [128][512]: rows 0:64 = Ws2^T, rows 64:128 = Wn2^T
            int bw = task - T4;                     // [0,64)
            int k0 = (bw & 15) * 32, n0 = (bw >> 4) * 32;
            const float* Wsrc = (n0 < 64) ? a.ws2 : a.wn2;
            int nb = (n0 < 64) ? n0 : n0 - 64;
            int tx = t & 31, ty = t >> 5;
            for (int i = ty; i < 32; i += 8)
                tile[i][tx] = Wsrc[(size_t)(k0 + i) * 64 + nb + tx];
            __syncthreads();
            for (int i = ty; i < 32; i += 8)
                a.WT2[(size_t)(n0 + i) * 512 + k0 + tx] = f2bf(tile[tx][i]);
            __syncthreads();
        }
    }
}

// ---------- agg (bf16 in, bf16 mean out), one wave per node, grid-strided ----------
__device__ void agg_phase(unsigned short* X, const int* eidx, const int* deg) {
    const int lane = threadIdx.x & 63;
    const int wave = threadIdx.x >> 6;
    for (int task = blockIdx.x; task < 2500; task += GRID) {
        const int node = task * 4 + wave;          // < 10000 exactly
        const int start = node * CAP;
        const int cnt = min(deg[node], CAP);
        float acc[8] = {0.f, 0.f, 0.f, 0.f, 0.f, 0.f, 0.f, 0.f};
        int j = 0;
        for (; j + 4 <= cnt; j += 4) {
            int4 s4 = *(const int4*)(eidx + start + j);
            u16x8 v0 = *(const u16x8*)(X + (size_t)s4.x * KK + lane * 8);
            u16x8 v1 = *(const u16x8*)(X + (size_t)s4.y * KK + lane * 8);
            u16x8 v2 = *(const u16x8*)(X + (size_t)s4.z * KK + lane * 8);
            u16x8 v3 = *(const u16x8*)(X + (size_t)s4.w * KK + lane * 8);
#pragma unroll
            for (int e = 0; e < 8; ++e)
                acc[e] += (bf2f(v0[e]) + bf2f(v1[e])) + (bf2f(v2[e]) + bf2f(v3[e]));
        }
        for (; j < cnt; ++j) {
            int s = eidx[start + j];
            u16x8 v = *(const u16x8*)(X + (size_t)s * KK + lane * 8);
#pragma unroll
            for (int e = 0; e < 8; ++e) acc[e] += bf2f(v[e]);
        }
        const float r = 1.0f / fmaxf((float)cnt, 1.0f);
        u16x8 o;
#pragma unroll
        for (int e = 0; e < 8; ++e) o[e] = f2bf(acc[e] * r);
        *(u16x8*)(X + (size_t)node * KK + 512 + lane * 8) = o;
    }
}

// ---------- MFMA GEMM phase: BMx128 tile, 4 waves 2x2, BK=64, 2-phase dbuf ----------
template <int BM, int KLEN, bool RELU, int MODE, int CBN>
__device__ void gemm_phase(const unsigned short* __restrict__ X,
                           const unsigned short* __restrict__ WT,
                           const float* __restrict__ bias,
                           unsigned short* __restrict__ Cbf,
                           float* __restrict__ Sf, unsigned short* __restrict__ Pb,
                           int ntask, char* ldsraw) {
    constexpr int ABYTES = BM * 128;        // A tile bytes (BM x 64 bf16)
    constexpr int BBYTES = 128 * 128;       // B tile bytes (128 x 64 bf16)
    constexpr int ACH = ABYTES / 4096;
    constexpr int FM = BM / 32;
    constexpr int NT = KLEN / 64;
    char* As = ldsraw;                      // 2*ABYTES
    char* Bs = ldsraw + 2 * ABYTES;         // 2*BBYTES

    const int bid = blockIdx.x;
    if (bid >= ntask) return;               // non-participants fall through to grid sync
    const int q = ntask >> 3, r = ntask & 7;
    const int xcd = bid & 7, bidx = bid >> 3;
    const int wgid = (xcd < r ? xcd * (q + 1) : r * (q + 1) + (xcd - r) * q) + bidx;
    const int r0 = (wgid / CBN) * BM;
    const int c0 = (wgid % CBN) * 128;

    const int t = threadIdx.x;
    const int lane = t & 63, wave = t >> 6;
    const int wr = wave >> 1, wc = wave & 1;
    const int rl = lane & 15, kg = lane >> 4;

    f32x4 acc[FM][4];
#pragma unroll
    for (int i = 0; i < FM; ++i)
#pragma unroll
        for (int j = 0; j < 4; ++j) acc[i][j] = (f32x4){0.f, 0.f, 0.f, 0.f};

    auto stage = [&](int buf, int k0) {
#pragma unroll
        for (int ch = 0; ch < ACH; ++ch) {
            int idx = ch * 4096 + t * 16;
            int row = idx >> 7;             // 128 B per LDS row
            int sl = (idx >> 4) & 7;
            int grow = min(r0 + row, NN - 1);
            const char* g = (const char*)X + (size_t)grow * KB + (size_t)(k0 * 2) +
                            ((sl ^ (row & 7)) << 4);
            gload16(g, As + buf * ABYTES + ch * 4096 + wave * 1024);
        }
#pragma unroll
        for (int ch = 0; ch < 4; ++ch) {
            int idx = ch * 4096 + t * 16;
            int row = idx >> 7;
            int sl = (idx >> 4) & 7;
            const char* g = (const char*)WT + (size_t)(c0 + row) * (KLEN * 2) +
                            (size_t)(k0 * 2) + ((sl ^ (row & 7)) << 4);
            gload16(g, Bs + buf * BBYTES + ch * 4096 + wave * 1024);
        }
    };

    stage(0, 0);
    __syncthreads();

    int cur = 0;
    for (int kt = 0; kt < NT; ++kt) {
        if (kt + 1 < NT) stage(cur ^ 1, (kt + 1) * 64);

        const char* Ab = As + cur * ABYTES;
        const char* Bb = Bs + cur * BBYTES;
#pragma unroll
        for (int ks = 0; ks < 2; ++ks) {
            bf16x8 af[FM], bfr[4];
#pragma unroll
            for (int mi = 0; mi < FM; ++mi) {
                int row = wr * (BM / 2) + mi * 16 + rl;
                int sl = ks * 4 + kg;
                af[mi] = *(const bf16x8*)(Ab + row * 128 + ((sl ^ (row & 7)) << 4));
            }
#pragma unroll
            for (int ni = 0; ni < 4; ++ni) {
                int row = wc * 64 + ni * 16 + rl;
                int sl = ks * 4 + kg;
                bfr[ni] = *(const bf16x8*)(Bb + row * 128 + ((sl ^ (row & 7)) << 4));
            }
#pragma unroll
            for (int mi = 0; mi < FM; ++mi)
#pragma unroll
                for (int ni = 0; ni < 4; ++ni)
                    acc[mi][ni] = __builtin_amdgcn_mfma_f32_16x16x32_bf16(
                        af[mi], bfr[ni], acc[mi][ni], 0, 0, 0);
        }
        __syncthreads();
        cur ^= 1;
    }

    const int ib = r0 + wr * (BM / 2) + (lane >> 4) * 4;
    const int jb0 = wc * 64 + (lane & 15);
#pragma unroll
    for (int mi = 0; mi < FM; ++mi)
#pragma unroll
        for (int ni = 0; ni < 4; ++ni) {
            int jl = jb0 + ni * 16;
#pragma unroll
            for (int reg = 0; reg < 4; ++reg) {
                int i = ib + mi * 16 + reg;
                if (i >= NN) continue;
                float v = acc[mi][ni][reg];
                if (MODE == 0) {
                    int j = c0 + jl;
                    v += bias[j];
                    if (RELU) v = fmaxf(v, 0.f);
                    Cbf[(size_t)i * KK + j] = f2bf(v);
                } else {
                    if (jl < 64) {
                        Sf[(size_t)i * 64 + jl] = v + bias[jl];
                    } else {
                        Pb[(size_t)i * 64 + (jl - 64)] = f2bf(v);
                    }
                }
            }
        }
}

// ---------- comb: mean-of-P gather + combine -> out, grid-strided ----------
__device__ void comb_phase(const Args& a) {
    const int lane = threadIdx.x & 63;
    const int wave = threadIdx.x >> 6;
    for (int task = blockIdx.x; task < 2500; task += GRID) {
        const int node = task * 4 + wave;
        const int start = node * CAP;
        const int cnt = min(a.cursor[node], CAP);
        float s = 0.f;
        int j = 0;
        for (; j + 4 <= cnt; j += 4) {
            int4 s4 = *(const int4*)(a.eidx + start + j);
            float p0 = bf2f(a.Pb[(size_t)s4.x * 64 + lane]);
            float p1 = bf2f(a.Pb[(size_t)s4.y * 64 + lane]);
            float p2 = bf2f(a.Pb[(size_t)s4.z * 64 + lane]);
            float p3 = bf2f(a.Pb[(size_t)s4.w * 64 + lane]);
            s += (p0 + p1) + (p2 + p3);
        }
        for (; j < cnt; ++j) {
            int sc = a.eidx[start + j];
            s += bf2f(a.Pb[(size_t)sc * 64 + lane]);
        }
        const float r = 1.0f / fmaxf((float)cnt, 1.0f);
        float v = a.Sf[(size_t)node * 64 + lane] + s * r;
        float o = a.flag[node] ? v * (1.0f + (float)a.cl[node])
                               : a.prev[(size_t)node * 64 + lane];
        a.out[(size_t)node * 64 + lane] = o;
    }
}

// ---------- cooperative megakernel: 9 phases, 7 grid syncs ----------
__global__ __launch_bounds__(NTHR, 3) void k_mega(Args a) {
    __shared__ __align__(16) char lds[49152];
    cg::grid_group gg = cg::this_grid();

    zero_phase(a);
    gg.sync();
    prep_phase(a, lds);
    gg.sync();
    agg_phase(a.XA, a.eidx, a.cursor);
    gg.sync();
    gemm_phase<64, 1024, true, 0, 4>(a.XA, a.WT0, a.b0, a.XB, nullptr, nullptr, GRID, lds);
    gg.sync();
    agg_phase(a.XB, a.eidx, a.cursor);
    gg.sync();
    gemm_phase<64, 1024, true, 0, 4>(a.XB, a.WT1, a.b1, a.XA, nullptr, nullptr, GRID, lds);
    gg.sync();
    gemm_phase<32, 512, false, 1, 1>(a.XA, a.WT2, a.b2, nullptr, a.Sf, a.Pb, 313, lds);
    gg.sync();
    comb_phase(a);
}

// ---------- fallback wrappers (same device code, separate launches) ----------
__global__ __launch_bounds__(NTHR, 3) void k_w_zero(Args a) { zero_phase(a); }
__global__ __launch_bounds__(NTHR, 3) void k_w_prep(Args a) {
    __shared__ __align__(16) char lds[49152];
    prep_phase(a, lds);
}
__global__ __launch_bounds__(NTHR, 3) void k_w_aggA(Args a) { agg_phase(a.XA, a.eidx, a.cursor); }
__global__ __launch_bounds__(NTHR, 3) void k_w_aggB(Args a) { agg_phase(a.XB, a.eidx, a.cursor); }
__global__ __launch_bounds__(NTHR, 3) void k_w_g0(Args a) {
    __shared__ __align__(16) char lds[49152];
    gemm_phase<64, 1024, true, 0, 4>(a.XA, a.WT0, a.b0, a.XB, nullptr, nullptr, GRID, lds);
}
__global__ __launch_bounds__(NTHR, 3) void k_w_g1(Args a) {
    __shared__ __align__(16) char lds[49152];
    gemm_phase<64, 1024, true, 0, 4>(a.XB, a.WT1, a.b1, a.XA, nullptr, nullptr, GRID, lds);
}
__global__ __launch_bounds__(NTHR, 3) void k_w_g2(Args a) {
    __shared__ __align__(16) char lds[49152];
    gemm_phase<32, 512, false, 1, 1>(a.XA, a.WT2, a.b2, nullptr, a.Sf, a.Pb, 313, lds);
}
__global__ __launch_bounds__(NTHR, 3) void k_w_comb(Args a) { comb_phase(a); }

extern "C" void kernel_launch(void* const* d_in, const int* in_sizes, int n_in,
                              void* d_out, int out_size, void* d_ws, size_t ws_size,
                              hipStream_t stream) {
    Args a;
    a.feat = (const float*)d_in[0];
    a.ws0  = (const float*)d_in[1];
    a.wn0  = (const float*)d_in[2];
    a.b0   = (const float*)d_in[3];
    a.ws1  = (const float*)d_in[4];
    a.wn1  = (const float*)d_in[5];
    a.b1   = (const float*)d_in[6];
    a.ws2  = (const float*)d_in[7];
    a.wn2  = (const float*)d_in[8];
    a.b2   = (const float*)d_in[9];
    a.prev = (const float*)d_in[10];
    a.esrc = (const int*)d_in[11];
    a.edst = (const int*)d_in[12];
    a.high = (const int*)d_in[13];
    a.low  = (const int*)d_in[14];
    a.E  = in_sizes[11];
    a.nh = in_sizes[13];
    a.nl = in_sizes[14];
    a.out = (float*)d_out;

    // workspace layout (bytes), total ~51.0 MB (same as R8)
    char* w = (char*)d_ws;
    a.XA  = (unsigned short*)(w + 0);         // [NN][1024] bf16
    a.XB  = (unsigned short*)(w + 20480000);  // [NN][1024] bf16
    a.WT0 = (unsigned short*)(w + 40960000);  // [512][1024] bf16
    a.WT1 = (unsigned short*)(w + 42008576);  // [512][1024] bf16
    a.WT2 = (unsigned short*)(w + 43057152);  // [128][512]  bf16
    a.Sf  = (float*)(w + 43188224);           // [NN][64] f32
    a.Pb  = (unsigned short*)(w + 45748224);  // [NN][64] bf16
    a.eidx   = (int*)(w + 47028224);          // [NN*CAP]
    a.cursor = (int*)(w + 50868224);          // [NN]  -- contiguous:
    a.flag   = (int*)(w + 50908224);          // [NN]     cursor|flag|cl
    a.cl     = (int*)(w + 50948224);          // [NN]

    void* params[] = {(void*)&a};
    hipError_t err = hipLaunchCooperativeKernel((const void*)k_mega, dim3(GRID),
                                                dim3(NTHR), params, 0, stream);
    if (err != hipSuccess) {
        // fallback: identical phases as separate launches (R8-equivalent chain)
        k_w_zero<<<GRID, NTHR, 0, stream>>>(a);
        k_w_prep<<<GRID, NTHR, 0, stream>>>(a);
        k_w_aggA<<<GRID, NTHR, 0, stream>>>(a);
        k_w_g0<<<GRID, NTHR, 0, stream>>>(a);
        k_w_aggB<<<GRID, NTHR, 0, stream>>>(a);
        k_w_g1<<<GRID, NTHR, 0, stream>>>(a);
        k_w_g2<<<GRID, NTHR, 0, stream>>>(a);
        k_w_comb<<<GRID, NTHR, 0, stream>>>(a);
    }
}

// Round 10
// 125.885 us; speedup vs baseline: 5.2854x; 5.2854x over previous
//
#include <hip/hip_runtime.h>
#include <stdint.h>

#define NN 10000
#define DIN 512
#define KK 1024   // X row length (bf16): [h | mean]
#define KB 2048   // X row bytes
#define CAP 96    // fixed per-node edge capacity (Poisson(16) degrees)

typedef __attribute__((ext_vector_type(8))) short bf16x8;
typedef __attribute__((ext_vector_type(8))) unsigned short u16x8;
typedef __attribute__((ext_vector_type(4))) float f32x4;

__device__ __forceinline__ float bf2f(unsigned short u) {
    return __uint_as_float(((unsigned)u) << 16);
}
__device__ __forceinline__ unsigned short f2bf(float x) {
    unsigned u = __float_as_uint(x);
    return (unsigned short)((u + 0x7fffu + ((u >> 16) & 1u)) >> 16);
}
__device__ __forceinline__ void gload16(const void* g, void* lds) {
    auto gp = reinterpret_cast<const __attribute__((address_space(1))) void*>(
        reinterpret_cast<uintptr_t>(g));
    auto lp = reinterpret_cast<__attribute__((address_space(3))) void*>(
        reinterpret_cast<uintptr_t>(lds));
    __builtin_amdgcn_global_load_lds(gp, lp, 16, 0, 0);
}

// ---------- zero cursor|flag|cl (contiguous 3*NN ints = 120 KB) ----------
__global__ __launch_bounds__(256) void k_zero(int4* __restrict__ p, int n4) {
    int i = blockIdx.x * 256 + threadIdx.x;
    if (i < n4) p[i] = make_int4(0, 0, 0, 0);
}

// ---------- mega prep: all independent tasks, block-range partitioned ----------
__global__ __launch_bounds__(256) void k_prep(
    const float* __restrict__ feat, unsigned short* __restrict__ XA,
    const int* __restrict__ esrc, const int* __restrict__ edst, int E, int CB,
    int* __restrict__ cursor, int* __restrict__ eidx,
    const int* __restrict__ high, int nh, const int* __restrict__ low, int nl, int MB,
    int* __restrict__ flag, int* __restrict__ cl,
    const float* __restrict__ ws0, const float* __restrict__ wn0,
    const float* __restrict__ ws1, const float* __restrict__ wn1,
    const float* __restrict__ ws2, const float* __restrict__ wn2,
    unsigned short* __restrict__ WT0, unsigned short* __restrict__ WT1,
    unsigned short* __restrict__ WT2) {
    __shared__ float tile[32][33];
    const int b = blockIdx.x;
    const int t = threadIdx.x;
    if (b < 2500) {
        int idx = b * 256 + t;                 // exactly NN*64 threads
        int row = idx >> 6;
        int col = (idx & 63) * 8;
        const float4* s = (const float4*)(feat + (size_t)row * DIN + col);
        float4 v0 = s[0], v1 = s[1];
        u16x8 o;
        o[0] = f2bf(v0.x); o[1] = f2bf(v0.y); o[2] = f2bf(v0.z); o[3] = f2bf(v0.w);
        o[4] = f2bf(v1.x); o[5] = f2bf(v1.y); o[6] = f2bf(v1.z); o[7] = f2bf(v1.w);
        *(u16x8*)(XA + (size_t)row * KK + col) = o;
    } else if (b < 2500 + CB) {
        int i = (b - 2500) * 256 + t;
        if (i < E) {
            int d = edst[i];
            int pos = atomicAdd(&cursor[d], 1);
            if (pos < CAP) eidx[d * CAP + pos] = esrc[i];
        }
    } else if (b < 2500 + CB + MB) {
        int i = (b - 2500 - CB) * 256 + t;
        if (i < nh) {
            atomicOr(&flag[high[i]], 1);
        } else if (i < nh + nl) {
            int r = low[i - nh];
            atomicOr(&flag[r], 1);
            atomicAdd(&cl[r], 1);
        }
    } else if (b < 2500 + CB + MB + 1024) {
        // WT0/WT1: WT[n][k] = bf16(k<512 ? Ws[k][n] : Wn[k-512][n])
        int bw = b - 2500 - CB - MB;
        const float* Ws = (bw < 512) ? ws0 : ws1;
        const float* Wn = (bw < 512) ? wn0 : wn1;
        unsigned short* WT = (bw < 512) ? WT0 : WT1;
        bw &= 511;
        int k0 = (bw & 31) * 32, n0 = (bw >> 5) * 32;
        const float* Wsrc = (k0 < 512) ? Ws : Wn;
        int kb = (k0 < 512) ? k0 : k0 - 512;
        int tx = t & 31, ty = t >> 5;
        for (int i = ty; i < 32; i += 8)
            tile[i][tx] = Wsrc[(size_t)(kb + i) * 512 + n0 + tx];
        __syncthreads();
        for (int i = ty; i < 32; i += 8)
            WT[(size_t)(n0 + i) * 1024 + k0 + tx] = f2bf(tile[tx][i]);
    } else {
        // WT2 [128][512]: rows 0:64 = Ws2^T, rows 64:128 = Wn2^T
        int bw = b - 2500 - CB - MB - 1024;   // [0,64)
        int k0 = (bw & 15) * 32, n0 = (bw >> 4) * 32;
        const float* Wsrc = (n0 < 64) ? ws2 : wn2;
        int nb = (n0 < 64) ? n0 : n0 - 64;
        int tx = t & 31, ty = t >> 5;
        for (int i = ty; i < 32; i += 8)
            tile[i][tx] = Wsrc[(size_t)(k0 + i) * 64 + nb + tx];
        __syncthreads();
        for (int i = ty; i < 32; i += 8)
            WT2[(size_t)(n0 + i) * 512 + k0 + tx] = f2bf(tile[tx][i]);
    }
}

// ---------- aggregation (bf16 in, bf16 mean out), one wave per node ----------
// 8-wide edge batches: 2x int4 index loads + 8 row-loads in flight (G7 MLP)
__global__ __launch_bounds__(256) void k_aggb(unsigned short* __restrict__ X,
                                              const int* __restrict__ eidx,
                                              const int* __restrict__ deg) {
    const int node = blockIdx.x * 4 + (threadIdx.x >> 6);
    if (node >= NN) return;
    const int lane = threadIdx.x & 63;
    const int start = node * CAP;
    const int cnt = min(deg[node], CAP);
    float a[8] = {0.f, 0.f, 0.f, 0.f, 0.f, 0.f, 0.f, 0.f};
    int j = 0;
    for (; j + 8 <= cnt; j += 8) {
        int4 s4 = *(const int4*)(eidx + start + j);
        int4 s5 = *(const int4*)(eidx + start + j + 4);
        u16x8 v0 = *(const u16x8*)(X + (size_t)s4.x * KK + lane * 8);
        u16x8 v1 = *(const u16x8*)(X + (size_t)s4.y * KK + lane * 8);
        u16x8 v2 = *(const u16x8*)(X + (size_t)s4.z * KK + lane * 8);
        u16x8 v3 = *(const u16x8*)(X + (size_t)s4.w * KK + lane * 8);
        u16x8 v4 = *(const u16x8*)(X + (size_t)s5.x * KK + lane * 8);
        u16x8 v5 = *(const u16x8*)(X + (size_t)s5.y * KK + lane * 8);
        u16x8 v6 = *(const u16x8*)(X + (size_t)s5.z * KK + lane * 8);
        u16x8 v7 = *(const u16x8*)(X + (size_t)s5.w * KK + lane * 8);
#pragma unroll
        for (int e = 0; e < 8; ++e)
            a[e] += ((bf2f(v0[e]) + bf2f(v1[e])) + (bf2f(v2[e]) + bf2f(v3[e]))) +
                    ((bf2f(v4[e]) + bf2f(v5[e])) + (bf2f(v6[e]) + bf2f(v7[e])));
    }
    for (; j + 4 <= cnt; j += 4) {
        int4 s4 = *(const int4*)(eidx + start + j);
        u16x8 v0 = *(const u16x8*)(X + (size_t)s4.x * KK + lane * 8);
        u16x8 v1 = *(const u16x8*)(X + (size_t)s4.y * KK + lane * 8);
        u16x8 v2 = *(const u16x8*)(X + (size_t)s4.z * KK + lane * 8);
        u16x8 v3 = *(const u16x8*)(X + (size_t)s4.w * KK + lane * 8);
#pragma unroll
        for (int e = 0; e < 8; ++e)
            a[e] += (bf2f(v0[e]) + bf2f(v1[e])) + (bf2f(v2[e]) + bf2f(v3[e]));
    }
    for (; j < cnt; ++j) {
        int s = eidx[start + j];
        u16x8 v = *(const u16x8*)(X + (size_t)s * KK + lane * 8);
#pragma unroll
        for (int e = 0; e < 8; ++e) a[e] += bf2f(v[e]);
    }
    const float r = 1.0f / fmaxf((float)cnt, 1.0f);
    u16x8 o;
#pragma unroll
    for (int e = 0; e < 8; ++e) o[e] = f2bf(a[e] * r);
    *(u16x8*)(X + (size_t)node * KK + 512 + lane * 8) = o;
}

// ---------- MFMA GEMM, BMx128 tile, 4 waves 2x2, BK=64, 2-phase dbuf ----------
// 1-D grid, bijective XCD remap (m204). Prefetch next K-tile before compute
// (T3 minimum-2-phase); one vmcnt drain + barrier per K-step.
template <int BM, int KLEN, bool RELU, int MODE, int CBN>
__global__ __launch_bounds__(256) void k_mfma(
    const unsigned short* __restrict__ X,   // A: stride 2048 B
    const unsigned short* __restrict__ WT,  // B: stride KLEN*2 B
    const float* __restrict__ bias,
    unsigned short* __restrict__ Cbf,
    float* __restrict__ Sf, unsigned short* __restrict__ Pb) {
    constexpr int ABYTES = BM * 128;        // A tile bytes (BM x 64 bf16)
    constexpr int BBYTES = 128 * 128;       // B tile bytes (128 x 64 bf16)
    constexpr int ACH = ABYTES / 4096;
    constexpr int FM = BM / 32;
    constexpr int NT = KLEN / 64;
    __shared__ __align__(16) char As[2 * ABYTES];
    __shared__ __align__(16) char Bs[2 * BBYTES];

    const int nwg = gridDim.x;
    const int bid = blockIdx.x;
    const int q = nwg >> 3, r = nwg & 7;
    const int xcd = bid & 7, bidx = bid >> 3;
    const int wgid = (xcd < r ? xcd * (q + 1) : r * (q + 1) + (xcd - r) * q) + bidx;
    const int r0 = (wgid / CBN) * BM;
    const int c0 = (wgid % CBN) * 128;

    const int t = threadIdx.x;
    const int lane = t & 63, wave = t >> 6;
    const int wr = wave >> 1, wc = wave & 1;
    const int rl = lane & 15, kg = lane >> 4;

    f32x4 acc[FM][4];
#pragma unroll
    for (int i = 0; i < FM; ++i)
#pragma unroll
        for (int j = 0; j < 4; ++j) acc[i][j] = (f32x4){0.f, 0.f, 0.f, 0.f};

    auto stage = [&](int buf, int k0) {
#pragma unroll
        for (int ch = 0; ch < ACH; ++ch) {
            int idx = ch * 4096 + t * 16;
            int row = idx >> 7;           // 128 B per LDS row
            int sl = (idx >> 4) & 7;
            int grow = min(r0 + row, NN - 1);
            const char* g = (const char*)X + (size_t)grow * KB + (size_t)(k0 * 2) +
                            ((sl ^ (row & 7)) << 4);
            gload16(g, As + buf * ABYTES + ch * 4096 + wave * 1024);
        }
#pragma unroll
        for (int ch = 0; ch < 4; ++ch) {
            int idx = ch * 4096 + t * 16;
            int row = idx >> 7;
            int sl = (idx >> 4) & 7;
            const char* g = (const char*)WT + (size_t)(c0 + row) * (KLEN * 2) +
                            (size_t)(k0 * 2) + ((sl ^ (row & 7)) << 4);
            gload16(g, Bs + buf * BBYTES + ch * 4096 + wave * 1024);
        }
    };

    stage(0, 0);
    __syncthreads();                      // vmcnt(0) drain: buf0 ready

    int cur = 0;
    for (int kt = 0; kt < NT; ++kt) {
        if (kt + 1 < NT) stage(cur ^ 1, (kt + 1) * 64);   // prefetch next tile

        const char* Ab = As + cur * ABYTES;
        const char* Bb = Bs + cur * BBYTES;
#pragma unroll
        for (int ks = 0; ks < 2; ++ks) {
            bf16x8 af[FM], bfr[4];
#pragma unroll
            for (int mi = 0; mi < FM; ++mi) {
                int row = wr * (BM / 2) + mi * 16 + rl;
                int sl = ks * 4 + kg;
                af[mi] = *(const bf16x8*)(Ab + row * 128 + ((sl ^ (row & 7)) << 4));
            }
#pragma unroll
            for (int ni = 0; ni < 4; ++ni) {
                int row = wc * 64 + ni * 16 + rl;
                int sl = ks * 4 + kg;
                bfr[ni] = *(const bf16x8*)(Bb + row * 128 + ((sl ^ (row & 7)) << 4));
            }
#pragma unroll
            for (int mi = 0; mi < FM; ++mi)
#pragma unroll
                for (int ni = 0; ni < 4; ++ni)
                    acc[mi][ni] = __builtin_amdgcn_mfma_f32_16x16x32_bf16(
                        af[mi], bfr[ni], acc[mi][ni], 0, 0, 0);
        }
        __syncthreads();                  // drains prefetch vmcnt + LDS reads
        cur ^= 1;
    }

    // epilogue: C/D layout col=lane&15, row=(lane>>4)*4+reg
    const int ib = r0 + wr * (BM / 2) + (lane >> 4) * 4;
    const int jb0 = wc * 64 + (lane & 15);
#pragma unroll
    for (int mi = 0; mi < FM; ++mi)
#pragma unroll
        for (int ni = 0; ni < 4; ++ni) {
            int jl = jb0 + ni * 16;
#pragma unroll
            for (int reg = 0; reg < 4; ++reg) {
                int i = ib + mi * 16 + reg;
                if (i >= NN) continue;
                float v = acc[mi][ni][reg];
                if (MODE == 0) {
                    int j = c0 + jl;
                    v += bias[j];
                    if (RELU) v = fmaxf(v, 0.f);
                    Cbf[(size_t)i * KK + j] = f2bf(v);
                } else {
                    if (jl < 64) {
                        Sf[(size_t)i * 64 + jl] = v + bias[jl];
                    } else {
                        Pb[(size_t)i * 64 + (jl - 64)] = f2bf(v);
                    }
                }
            }
        }
}

// ---------- fused: mean-of-P gather + combine -> out (8-wide MLP) ----------
__global__ __launch_bounds__(256) void k_comb(const float* __restrict__ Sf,
                                              const unsigned short* __restrict__ Pb,
                                              const int* __restrict__ eidx,
                                              const int* __restrict__ deg,
                                              const int* __restrict__ flag,
                                              const int* __restrict__ cl,
                                              const float* __restrict__ prev,
                                              float* __restrict__ out) {
    const int node = blockIdx.x * 4 + (threadIdx.x >> 6);
    if (node >= NN) return;
    const int lane = threadIdx.x & 63;
    const int start = node * CAP;
    const int cnt = min(deg[node], CAP);
    float a = 0.f;
    int j = 0;
    for (; j + 8 <= cnt; j += 8) {
        int4 s4 = *(const int4*)(eidx + start + j);
        int4 s5 = *(const int4*)(eidx + start + j + 4);
        float p0 = bf2f(Pb[(size_t)s4.x * 64 + lane]);
        float p1 = bf2f(Pb[(size_t)s4.y * 64 + lane]);
        float p2 = bf2f(Pb[(size_t)s4.z * 64 + lane]);
        float p3 = bf2f(Pb[(size_t)s4.w * 64 + lane]);
        float p4 = bf2f(Pb[(size_t)s5.x * 64 + lane]);
        float p5 = bf2f(Pb[(size_t)s5.y * 64 + lane]);
        float p6 = bf2f(Pb[(size_t)s5.z * 64 + lane]);
        float p7 = bf2f(Pb[(size_t)s5.w * 64 + lane]);
        a += ((p0 + p1) + (p2 + p3)) + ((p4 + p5) + (p6 + p7));
    }
    for (; j < cnt; ++j) {
        int s = eidx[start + j];
        a += bf2f(Pb[(size_t)s * 64 + lane]);
    }
    const float r = 1.0f / fmaxf((float)cnt, 1.0f);
    float v = Sf[(size_t)node * 64 + lane] + a * r;
    float o = flag[node] ? v * (1.0f + (float)cl[node])
                         : prev[(size_t)node * 64 + lane];
    out[(size_t)node * 64 + lane] = o;
}

extern "C" void kernel_launch(void* const* d_in, const int* in_sizes, int n_in,
                              void* d_out, int out_size, void* d_ws, size_t ws_size,
                              hipStream_t stream) {
    const float* feat = (const float*)d_in[0];
    const float* ws0  = (const float*)d_in[1];
    const float* wn0  = (const float*)d_in[2];
    const float* b0   = (const float*)d_in[3];
    const float* ws1  = (const float*)d_in[4];
    const float* wn1  = (const float*)d_in[5];
    const float* b1   = (const float*)d_in[6];
    const float* ws2  = (const float*)d_in[7];
    const float* wn2  = (const float*)d_in[8];
    const float* b2   = (const float*)d_in[9];
    const float* prev = (const float*)d_in[10];
    const int* esrc = (const int*)d_in[11];
    const int* edst = (const int*)d_in[12];
    const int* high = (const int*)d_in[13];
    const int* low  = (const int*)d_in[14];
    const int E  = in_sizes[11];
    const int nh = in_sizes[13];
    const int nl = in_sizes[14];
    float* out = (float*)d_out;

    // workspace layout (bytes), total ~51.0 MB
    char* w = (char*)d_ws;
    unsigned short* XA  = (unsigned short*)(w + 0);         // [NN][1024] bf16
    unsigned short* XB  = (unsigned short*)(w + 20480000);  // [NN][1024] bf16
    unsigned short* WT0 = (unsigned short*)(w + 40960000);  // [512][1024] bf16
    unsigned short* WT1 = (unsigned short*)(w + 42008576);  // [512][1024] bf16
    unsigned short* WT2 = (unsigned short*)(w + 43057152);  // [128][512]  bf16
    float* Sf   = (float*)(w + 43188224);                   // [NN][64] f32
    unsigned short* Pb = (unsigned short*)(w + 45748224);   // [NN][64] bf16
    int*   eidx   = (int*)  (w + 47028224);                 // [NN*CAP]
    int*   cursor = (int*)  (w + 50868224);                 // [NN]  -- contiguous:
    int*   flag   = (int*)  (w + 50908224);                 // [NN]     cursor|flag|cl
    int*   cl     = (int*)  (w + 50948224);                 // [NN]

    const int CB = (E + 255) / 256;              // 625
    const int MB = (nh + nl + 255) / 256;        // 4
    const int gemmBig = ((NN + 63) / 64) * 4;    // 628 blocks (~2.5/CU)
    const int gemmSm  = (NN + 31) / 32;          // 313 blocks
    const int aggGrid = (NN + 3) / 4;            // 2500

    const int n4 = 3 * NN / 4;                   // 7500 int4
    k_zero<<<(n4 + 255) / 256, 256, 0, stream>>>((int4*)cursor, n4);
    k_prep<<<2500 + CB + MB + 1024 + 64, 256, 0, stream>>>(
        feat, XA, esrc, edst, E, CB, cursor, eidx,
        high, nh, low, nl, MB, flag, cl,
        ws0, wn0, ws1, wn1, ws2, wn2, WT0, WT1, WT2);

    // layer 0
    k_aggb<<<aggGrid, 256, 0, stream>>>(XA, eidx, cursor);
    k_mfma<64, 1024, true, 0, 4><<<gemmBig, 256, 0, stream>>>(XA, WT0, b0, XB, nullptr, nullptr);
    // layer 1
    k_aggb<<<aggGrid, 256, 0, stream>>>(XB, eidx, cursor);
    k_mfma<64, 1024, true, 0, 4><<<gemmBig, 256, 0, stream>>>(XB, WT1, b1, XA, nullptr, nullptr);
    // layer 2: [S|P] = H1 @ [Ws2|Wn2]  (mean/projection commute)
    k_mfma<32, 512, false, 1, 1><<<gemmSm, 256, 0, stream>>>(XA, WT2, b2, nullptr, Sf, Pb);
    // fused mean(P) + combine
    k_comb<<<aggGrid, 256, 0, stream>>>(Sf, Pb, eidx, cursor, flag, cl, prev, out);
}

// Round 11
// 120.342 us; speedup vs baseline: 5.5289x; 1.0461x over previous
//
#include <hip/hip_runtime.h>
#include <stdint.h>

#define NN 10000
#define DIN 512
#define KK 1024   // X row length (bf16): [h | mean]
#define KB 2048   // X row bytes
#define CAP 96    // fixed per-node edge capacity (Poisson(16) degrees)

typedef __attribute__((ext_vector_type(8))) short bf16x8;
typedef __attribute__((ext_vector_type(8))) unsigned short u16x8;
typedef __attribute__((ext_vector_type(4))) float f32x4;

__device__ __forceinline__ float bf2f(unsigned short u) {
    return __uint_as_float(((unsigned)u) << 16);
}
__device__ __forceinline__ unsigned short f2bf(float x) {
    unsigned u = __float_as_uint(x);
    return (unsigned short)((u + 0x7fffu + ((u >> 16) & 1u)) >> 16);
}
__device__ __forceinline__ void gload16(const void* g, void* lds) {
    auto gp = reinterpret_cast<const __attribute__((address_space(1))) void*>(
        reinterpret_cast<uintptr_t>(g));
    auto lp = reinterpret_cast<__attribute__((address_space(3))) void*>(
        reinterpret_cast<uintptr_t>(lds));
    __builtin_amdgcn_global_load_lds(gp, lp, 16, 0, 0);
}

// ---------- zero cursor|flag|cl (contiguous 3*NN ints = 120 KB) ----------
__global__ __launch_bounds__(256) void k_zero(int4* __restrict__ p, int n4) {
    int i = blockIdx.x * 256 + threadIdx.x;
    if (i < n4) p[i] = make_int4(0, 0, 0, 0);
}

// ---------- mega prep: all independent tasks, block-range partitioned ----------
__global__ __launch_bounds__(256) void k_prep(
    const float* __restrict__ feat, unsigned short* __restrict__ XA,
    const int* __restrict__ esrc, const int* __restrict__ edst, int E, int CB,
    int* __restrict__ cursor, int* __restrict__ eidx,
    const int* __restrict__ high, int nh, const int* __restrict__ low, int nl, int MB,
    int* __restrict__ flag, int* __restrict__ cl,
    const float* __restrict__ ws0, const float* __restrict__ wn0,
    const float* __restrict__ ws1, const float* __restrict__ wn1,
    const float* __restrict__ ws2, const float* __restrict__ wn2,
    unsigned short* __restrict__ WT0, unsigned short* __restrict__ WT1,
    unsigned short* __restrict__ WT2) {
    __shared__ float tile[32][33];
    const int b = blockIdx.x;
    const int t = threadIdx.x;
    if (b < 2500) {
        int idx = b * 256 + t;                 // exactly NN*64 threads
        int row = idx >> 6;
        int col = (idx & 63) * 8;
        const float4* s = (const float4*)(feat + (size_t)row * DIN + col);
        float4 v0 = s[0], v1 = s[1];
        u16x8 o;
        o[0] = f2bf(v0.x); o[1] = f2bf(v0.y); o[2] = f2bf(v0.z); o[3] = f2bf(v0.w);
        o[4] = f2bf(v1.x); o[5] = f2bf(v1.y); o[6] = f2bf(v1.z); o[7] = f2bf(v1.w);
        *(u16x8*)(XA + (size_t)row * KK + col) = o;
    } else if (b < 2500 + CB) {
        int i = (b - 2500) * 256 + t;
        if (i < E) {
            int d = edst[i];
            int pos = atomicAdd(&cursor[d], 1);
            if (pos < CAP) eidx[d * CAP + pos] = esrc[i];
        }
    } else if (b < 2500 + CB + MB) {
        int i = (b - 2500 - CB) * 256 + t;
        if (i < nh) {
            atomicOr(&flag[high[i]], 1);
        } else if (i < nh + nl) {
            int r = low[i - nh];
            atomicOr(&flag[r], 1);
            atomicAdd(&cl[r], 1);
        }
    } else if (b < 2500 + CB + MB + 1024) {
        // WT0/WT1: WT[n][k] = bf16(k<512 ? Ws[k][n] : Wn[k-512][n])
        int bw = b - 2500 - CB - MB;
        const float* Ws = (bw < 512) ? ws0 : ws1;
        const float* Wn = (bw < 512) ? wn0 : wn1;
        unsigned short* WT = (bw < 512) ? WT0 : WT1;
        bw &= 511;
        int k0 = (bw & 31) * 32, n0 = (bw >> 5) * 32;
        const float* Wsrc = (k0 < 512) ? Ws : Wn;
        int kb = (k0 < 512) ? k0 : k0 - 512;
        int tx = t & 31, ty = t >> 5;
        for (int i = ty; i < 32; i += 8)
            tile[i][tx] = Wsrc[(size_t)(kb + i) * 512 + n0 + tx];
        __syncthreads();
        for (int i = ty; i < 32; i += 8)
            WT[(size_t)(n0 + i) * 1024 + k0 + tx] = f2bf(tile[tx][i]);
    } else {
        // WT2 [128][512]: rows 0:64 = Ws2^T, rows 64:128 = Wn2^T
        int bw = b - 2500 - CB - MB - 1024;   // [0,64)
        int k0 = (bw & 15) * 32, n0 = (bw >> 4) * 32;
        const float* Wsrc = (n0 < 64) ? ws2 : wn2;
        int nb = (n0 < 64) ? n0 : n0 - 64;
        int tx = t & 31, ty = t >> 5;
        for (int i = ty; i < 32; i += 8)
            tile[i][tx] = Wsrc[(size_t)(k0 + i) * 64 + nb + tx];
        __syncthreads();
        for (int i = ty; i < 32; i += 8)
            WT2[(size_t)(n0 + i) * 512 + k0 + tx] = f2bf(tile[tx][i]);
    }
}

// ---------- aggregation (bf16 in, bf16 mean out), one wave per node ----------
__global__ __launch_bounds__(256) void k_aggb(unsigned short* __restrict__ X,
                                              const int* __restrict__ eidx,
                                              const int* __restrict__ deg) {
    const int node = blockIdx.x * 4 + (threadIdx.x >> 6);
    if (node >= NN) return;
    const int lane = threadIdx.x & 63;
    const int start = node * CAP;
    const int cnt = min(deg[node], CAP);
    float a[8] = {0.f, 0.f, 0.f, 0.f, 0.f, 0.f, 0.f, 0.f};
    int j = 0;
    for (; j + 8 <= cnt; j += 8) {
        int4 s4 = *(const int4*)(eidx + start + j);
        int4 s5 = *(const int4*)(eidx + start + j + 4);
        u16x8 v0 = *(const u16x8*)(X + (size_t)s4.x * KK + lane * 8);
        u16x8 v1 = *(const u16x8*)(X + (size_t)s4.y * KK + lane * 8);
        u16x8 v2 = *(const u16x8*)(X + (size_t)s4.z * KK + lane * 8);
        u16x8 v3 = *(const u16x8*)(X + (size_t)s4.w * KK + lane * 8);
        u16x8 v4 = *(const u16x8*)(X + (size_t)s5.x * KK + lane * 8);
        u16x8 v5 = *(const u16x8*)(X + (size_t)s5.y * KK + lane * 8);
        u16x8 v6 = *(const u16x8*)(X + (size_t)s5.z * KK + lane * 8);
        u16x8 v7 = *(const u16x8*)(X + (size_t)s5.w * KK + lane * 8);
#pragma unroll
        for (int e = 0; e < 8; ++e)
            a[e] += ((bf2f(v0[e]) + bf2f(v1[e])) + (bf2f(v2[e]) + bf2f(v3[e]))) +
                    ((bf2f(v4[e]) + bf2f(v5[e])) + (bf2f(v6[e]) + bf2f(v7[e])));
    }
    for (; j + 4 <= cnt; j += 4) {
        int4 s4 = *(const int4*)(eidx + start + j);
        u16x8 v0 = *(const u16x8*)(X + (size_t)s4.x * KK + lane * 8);
        u16x8 v1 = *(const u16x8*)(X + (size_t)s4.y * KK + lane * 8);
        u16x8 v2 = *(const u16x8*)(X + (size_t)s4.z * KK + lane * 8);
        u16x8 v3 = *(const u16x8*)(X + (size_t)s4.w * KK + lane * 8);
#pragma unroll
        for (int e = 0; e < 8; ++e)
            a[e] += (bf2f(v0[e]) + bf2f(v1[e])) + (bf2f(v2[e]) + bf2f(v3[e]));
    }
    for (; j < cnt; ++j) {
        int s = eidx[start + j];
        u16x8 v = *(const u16x8*)(X + (size_t)s * KK + lane * 8);
#pragma unroll
        for (int e = 0; e < 8; ++e) a[e] += bf2f(v[e]);
    }
    const float r = 1.0f / fmaxf((float)cnt, 1.0f);
    u16x8 o;
#pragma unroll
    for (int e = 0; e < 8; ++e) o[e] = f2bf(a[e] * r);
    *(u16x8*)(X + (size_t)node * KK + 512 + lane * 8) = o;
}

// ---------- MFMA GEMM, BMx128 tile, 4 waves 2x2, BK=64, 2-phase dbuf ----------
// 1-D grid, bijective XCD remap (m204). Prefetch next K-tile before compute;
// one vmcnt drain + barrier per K-step. MODE 0 epilogue stages C through LDS
// (row stride 272 B => <=2-way bank conflict, free per m136) for coalesced
// 16B/lane global stores (was 32 scalar 2B scatter-stores per thread).
// MODE 1: j<64 -> Sf[i*64+j]=v+bias[j] (f32); j>=64 -> Pb[i*64+j-64]=bf16(v)
template <int BM, int KLEN, bool RELU, int MODE, int CBN>
__global__ __launch_bounds__(256) void k_mfma(
    const unsigned short* __restrict__ X,   // A: stride 2048 B
    const unsigned short* __restrict__ WT,  // B: stride KLEN*2 B
    const float* __restrict__ bias,
    unsigned short* __restrict__ Cbf,
    float* __restrict__ Sf, unsigned short* __restrict__ Pb) {
    constexpr int ABYTES = BM * 128;        // A tile bytes (BM x 64 bf16)
    constexpr int BBYTES = 128 * 128;       // B tile bytes (128 x 64 bf16)
    constexpr int ACH = ABYTES / 4096;
    constexpr int FM = BM / 32;
    constexpr int NT = KLEN / 64;
    __shared__ __align__(16) char As[2 * ABYTES];
    __shared__ __align__(16) char Bs[2 * BBYTES];

    const int nwg = gridDim.x;
    const int bid = blockIdx.x;
    const int q = nwg >> 3, r = nwg & 7;
    const int xcd = bid & 7, bidx = bid >> 3;
    const int wgid = (xcd < r ? xcd * (q + 1) : r * (q + 1) + (xcd - r) * q) + bidx;
    const int r0 = (wgid / CBN) * BM;
    const int c0 = (wgid % CBN) * 128;

    const int t = threadIdx.x;
    const int lane = t & 63, wave = t >> 6;
    const int wr = wave >> 1, wc = wave & 1;
    const int rl = lane & 15, kg = lane >> 4;

    f32x4 acc[FM][4];
#pragma unroll
    for (int i = 0; i < FM; ++i)
#pragma unroll
        for (int j = 0; j < 4; ++j) acc[i][j] = (f32x4){0.f, 0.f, 0.f, 0.f};

    auto stage = [&](int buf, int k0) {
#pragma unroll
        for (int ch = 0; ch < ACH; ++ch) {
            int idx = ch * 4096 + t * 16;
            int row = idx >> 7;           // 128 B per LDS row
            int sl = (idx >> 4) & 7;
            int grow = min(r0 + row, NN - 1);
            const char* g = (const char*)X + (size_t)grow * KB + (size_t)(k0 * 2) +
                            ((sl ^ (row & 7)) << 4);
            gload16(g, As + buf * ABYTES + ch * 4096 + wave * 1024);
        }
#pragma unroll
        for (int ch = 0; ch < 4; ++ch) {
            int idx = ch * 4096 + t * 16;
            int row = idx >> 7;
            int sl = (idx >> 4) & 7;
            const char* g = (const char*)WT + (size_t)(c0 + row) * (KLEN * 2) +
                            (size_t)(k0 * 2) + ((sl ^ (row & 7)) << 4);
            gload16(g, Bs + buf * BBYTES + ch * 4096 + wave * 1024);
        }
    };

    stage(0, 0);
    __syncthreads();                      // vmcnt(0) drain: buf0 ready

    int cur = 0;
    for (int kt = 0; kt < NT; ++kt) {
        if (kt + 1 < NT) stage(cur ^ 1, (kt + 1) * 64);   // prefetch next tile

        const char* Ab = As + cur * ABYTES;
        const char* Bb = Bs + cur * BBYTES;
#pragma unroll
        for (int ks = 0; ks < 2; ++ks) {
            bf16x8 af[FM], bfr[4];
#pragma unroll
            for (int mi = 0; mi < FM; ++mi) {
                int row = wr * (BM / 2) + mi * 16 + rl;
                int sl = ks * 4 + kg;
                af[mi] = *(const bf16x8*)(Ab + row * 128 + ((sl ^ (row & 7)) << 4));
            }
#pragma unroll
            for (int ni = 0; ni < 4; ++ni) {
                int row = wc * 64 + ni * 16 + rl;
                int sl = ks * 4 + kg;
                bfr[ni] = *(const bf16x8*)(Bb + row * 128 + ((sl ^ (row & 7)) << 4));
            }
#pragma unroll
            for (int mi = 0; mi < FM; ++mi)
#pragma unroll
                for (int ni = 0; ni < 4; ++ni)
                    acc[mi][ni] = __builtin_amdgcn_mfma_f32_16x16x32_bf16(
                        af[mi], bfr[ni], acc[mi][ni], 0, 0, 0);
        }
        __syncthreads();                  // drains prefetch vmcnt + LDS reads
        cur ^= 1;
    }

    // epilogue: C/D layout col=lane&15, row=(lane>>4)*4+reg
    if (MODE == 0) {
        constexpr int CSTRIDE = 272;      // bytes per LDS C row (128*2 + 16 pad)
        char* Cs = Bs;                    // reuse B staging (32 KB >= BM*272)
        const int clc = wc * 64 + (lane & 15);
        const float bj0 = bias[c0 + clc];
        const float bj1 = bias[c0 + clc + 16];
        const float bj2 = bias[c0 + clc + 32];
        const float bj3 = bias[c0 + clc + 48];
#pragma unroll
        for (int mi = 0; mi < FM; ++mi)
#pragma unroll
            for (int ni = 0; ni < 4; ++ni) {
                const float bj = (ni == 0) ? bj0 : (ni == 1) ? bj1 : (ni == 2) ? bj2 : bj3;
                const int cl_ = clc + ni * 16;
#pragma unroll
                for (int reg = 0; reg < 4; ++reg) {
                    int rl_ = wr * (BM / 2) + mi * 16 + (lane >> 4) * 4 + reg;
                    float v = acc[mi][ni][reg] + bj;
                    if (RELU) v = fmaxf(v, 0.f);
                    *(unsigned short*)(Cs + rl_ * CSTRIDE + cl_ * 2) = f2bf(v);
                }
            }
        __syncthreads();
#pragma unroll
        for (int ch = 0; ch < BM / 16; ++ch) {
            int rl_ = ch * 16 + (t >> 4);
            int cl_ = (t & 15) * 8;
            int i = r0 + rl_;
            if (i < NN) {
                u16x8 v = *(const u16x8*)(Cs + rl_ * CSTRIDE + cl_ * 2);
                *(u16x8*)(Cbf + (size_t)i * KK + c0 + cl_) = v;
            }
        }
    } else {
        const int ib = r0 + wr * (BM / 2) + (lane >> 4) * 4;
        const int jb0 = wc * 64 + (lane & 15);
#pragma unroll
        for (int mi = 0; mi < FM; ++mi)
#pragma unroll
            for (int ni = 0; ni < 4; ++ni) {
                int jl = jb0 + ni * 16;
#pragma unroll
                for (int reg = 0; reg < 4; ++reg) {
                    int i = ib + mi * 16 + reg;
                    if (i >= NN) continue;
                    float v = acc[mi][ni][reg];
                    if (jl < 64) {
                        Sf[(size_t)i * 64 + jl] = v + bias[jl];
                    } else {
                        Pb[(size_t)i * 64 + (jl - 64)] = f2bf(v);
                    }
                }
            }
    }
}

// ---------- fused: mean-of-P gather + combine -> out (8-wide MLP) ----------
__global__ __launch_bounds__(256) void k_comb(const float* __restrict__ Sf,
                                              const unsigned short* __restrict__ Pb,
                                              const int* __restrict__ eidx,
                                              const int* __restrict__ deg,
                                              const int* __restrict__ flag,
                                              const int* __restrict__ cl,
                                              const float* __restrict__ prev,
                                              float* __restrict__ out) {
    const int node = blockIdx.x * 4 + (threadIdx.x >> 6);
    if (node >= NN) return;
    const int lane = threadIdx.x & 63;
    const int start = node * CAP;
    const int cnt = min(deg[node], CAP);
    float a = 0.f;
    int j = 0;
    for (; j + 8 <= cnt; j += 8) {
        int4 s4 = *(const int4*)(eidx + start + j);
        int4 s5 = *(const int4*)(eidx + start + j + 4);
        float p0 = bf2f(Pb[(size_t)s4.x * 64 + lane]);
        float p1 = bf2f(Pb[(size_t)s4.y * 64 + lane]);
        float p2 = bf2f(Pb[(size_t)s4.z * 64 + lane]);
        float p3 = bf2f(Pb[(size_t)s4.w * 64 + lane]);
        float p4 = bf2f(Pb[(size_t)s5.x * 64 + lane]);
        float p5 = bf2f(Pb[(size_t)s5.y * 64 + lane]);
        float p6 = bf2f(Pb[(size_t)s5.z * 64 + lane]);
        float p7 = bf2f(Pb[(size_t)s5.w * 64 + lane]);
        a += ((p0 + p1) + (p2 + p3)) + ((p4 + p5) + (p6 + p7));
    }
    for (; j < cnt; ++j) {
        int s = eidx[start + j];
        a += bf2f(Pb[(size_t)s * 64 + lane]);
    }
    const float r = 1.0f / fmaxf((float)cnt, 1.0f);
    float v = Sf[(size_t)node * 64 + lane] + a * r;
    float o = flag[node] ? v * (1.0f + (float)cl[node])
                         : prev[(size_t)node * 64 + lane];
    out[(size_t)node * 64 + lane] = o;
}

extern "C" void kernel_launch(void* const* d_in, const int* in_sizes, int n_in,
                              void* d_out, int out_size, void* d_ws, size_t ws_size,
                              hipStream_t stream) {
    const float* feat = (const float*)d_in[0];
    const float* ws0  = (const float*)d_in[1];
    const float* wn0  = (const float*)d_in[2];
    const float* b0   = (const float*)d_in[3];
    const float* ws1  = (const float*)d_in[4];
    const float* wn1  = (const float*)d_in[5];
    const float* b1   = (const float*)d_in[6];
    const float* ws2  = (const float*)d_in[7];
    const float* wn2  = (const float*)d_in[8];
    const float* b2   = (const float*)d_in[9];
    const float* prev = (const float*)d_in[10];
    const int* esrc = (const int*)d_in[11];
    const int* edst = (const int*)d_in[12];
    const int* high = (const int*)d_in[13];
    const int* low  = (const int*)d_in[14];
    const int E  = in_sizes[11];
    const int nh = in_sizes[13];
    const int nl = in_sizes[14];
    float* out = (float*)d_out;

    // workspace layout (bytes), total ~51.0 MB
    char* w = (char*)d_ws;
    unsigned short* XA  = (unsigned short*)(w + 0);         // [NN][1024] bf16
    unsigned short* XB  = (unsigned short*)(w + 20480000);  // [NN][1024] bf16
    unsigned short* WT0 = (unsigned short*)(w + 40960000);  // [512][1024] bf16
    unsigned short* WT1 = (unsigned short*)(w + 42008576);  // [512][1024] bf16
    unsigned short* WT2 = (unsigned short*)(w + 43057152);  // [128][512]  bf16
    float* Sf   = (float*)(w + 43188224);                   // [NN][64] f32
    unsigned short* Pb = (unsigned short*)(w + 45748224);   // [NN][64] bf16
    int*   eidx   = (int*)  (w + 47028224);                 // [NN*CAP]
    int*   cursor = (int*)  (w + 50868224);                 // [NN]  -- contiguous:
    int*   flag   = (int*)  (w + 50908224);                 // [NN]     cursor|flag|cl
    int*   cl     = (int*)  (w + 50948224);                 // [NN]

    const int CB = (E + 255) / 256;              // 625
    const int MB = (nh + nl + 255) / 256;        // 4
    const int gemmBig = ((NN + 63) / 64) * 4;    // 628 blocks (~2.5/CU)
    const int gemmSm  = (NN + 31) / 32;          // 313 blocks
    const int aggGrid = (NN + 3) / 4;            // 2500

    const int n4 = 3 * NN / 4;                   // 7500 int4
    k_zero<<<(n4 + 255) / 256, 256, 0, stream>>>((int4*)cursor, n4);
    k_prep<<<2500 + CB + MB + 1024 + 64, 256, 0, stream>>>(
        feat, XA, esrc, edst, E, CB, cursor, eidx,
        high, nh, low, nl, MB, flag, cl,
        ws0, wn0, ws1, wn1, ws2, wn2, WT0, WT1, WT2);

    // layer 0
    k_aggb<<<aggGrid, 256, 0, stream>>>(XA, eidx, cursor);
    k_mfma<64, 1024, true, 0, 4><<<gemmBig, 256, 0, stream>>>(XA, WT0, b0, XB, nullptr, nullptr);
    // layer 1
    k_aggb<<<aggGrid, 256, 0, stream>>>(XB, eidx, cursor);
    k_mfma<64, 1024, true, 0, 4><<<gemmBig, 256, 0, stream>>>(XB, WT1, b1, XA, nullptr, nullptr);
    // layer 2: [S|P] = H1 @ [Ws2|Wn2]  (mean/projection commute)
    k_mfma<32, 512, false, 1, 1><<<gemmSm, 256, 0, stream>>>(XA, WT2, b2, nullptr, Sf, Pb);
    // fused mean(P) + combine
    k_comb<<<aggGrid, 256, 0, stream>>>(Sf, Pb, eidx, cursor, flag, cl, prev, out);
}